// Round 6
// baseline (890.353 us; speedup 1.0000x reference)
//
#include <hip/hip_runtime.h>
#include <math.h>

#define BB 32
#define TT 128
#define EE 128
#define HD 128
#define G4 512   // 4*H
#define NV 32000

typedef _Float16 f16x2 __attribute__((ext_vector_type(2)));
typedef _Float16 f16x8 __attribute__((ext_vector_type(8)));
typedef float    f32x4 __attribute__((ext_vector_type(4)));

// ---------------- Kernel A: Z0x = emb[inputs] @ W0 + b0 ----------------
__global__ __launch_bounds__(256) void k_embed_w0(
    const int* __restrict__ inputs, const float* __restrict__ emb,
    const float* __restrict__ W0, const float* __restrict__ b0,
    float* __restrict__ Z0x)
{
    __shared__ float xs[8][EE];
    const int r0 = blockIdx.x * 8;
    const int tid = threadIdx.x;
    for (int i = tid; i < 8 * EE; i += 256) {
        int r = i >> 7, e = i & 127;
        int tok = inputs[r0 + r];
        xs[r][e] = emb[tok * EE + e];
    }
    __syncthreads();
    const int c2 = tid * 2;
    float2 bb2 = *(const float2*)&b0[c2];
    float acc[8][2];
    #pragma unroll
    for (int r = 0; r < 8; ++r) { acc[r][0] = bb2.x; acc[r][1] = bb2.y; }
    for (int e = 0; e < EE; ++e) {
        float2 w = *(const float2*)&W0[e * G4 + c2];
        #pragma unroll
        for (int r = 0; r < 8; ++r) {
            float x = xs[r][e];
            acc[r][0] = fmaf(x, w.x, acc[r][0]);
            acc[r][1] = fmaf(x, w.y, acc[r][1]);
        }
    }
    #pragma unroll
    for (int r = 0; r < 8; ++r) {
        float2 o2; o2.x = acc[r][0]; o2.y = acc[r][1];
        *(float2*)&Z0x[(size_t)(r0 + r) * G4 + c2] = o2;
    }
}

// ---------------- Kernel B: 2-layer LSTM, one block per batch ----------------
// 32 blocks x 512 threads. f16 register-resident weights (192 VGPR),
// h via LDS as f16 read with float4 (b128) vector loads: 48 LDS instr/step.
__global__ __launch_bounds__(512, 2) void k_lstm_f2(
    const float* __restrict__ Z0x,
    const float* __restrict__ U0, const float* __restrict__ W1,
    const float* __restrict__ U1, const float* __restrict__ b1,
    float* __restrict__ y)
{
    const int b = blockIdx.x;
    const int tid = threadIdx.x;

    __shared__ _Float16 h0p[HD];
    __shared__ _Float16 h1p[HD];
    __shared__ float zb[G4];
    __shared__ float zu[G4];

    f16x2 u0c[64], w1c[64], u1c[64];
    #pragma unroll
    for (int e2 = 0; e2 < 64; ++e2) {
        u0c[e2] = f16x2{(_Float16)U0[(2 * e2) * G4 + tid], (_Float16)U0[(2 * e2 + 1) * G4 + tid]};
        w1c[e2] = f16x2{(_Float16)W1[(2 * e2) * G4 + tid], (_Float16)W1[(2 * e2 + 1) * G4 + tid]};
        u1c[e2] = f16x2{(_Float16)U1[(2 * e2) * G4 + tid], (_Float16)U1[(2 * e2 + 1) * G4 + tid]};
    }

    const float b1c = b1[tid];
    const float* __restrict__ zrow = Z0x + (size_t)b * TT * G4 + tid;

    float c0 = 0.f, c1 = 0.f;
    if (tid < HD) { h0p[tid] = (_Float16)0.f; h1p[tid] = (_Float16)0.f; }
    __syncthreads();

    const float4* h0q = (const float4*)h0p;   // 16 float4 = 128 f16
    const float4* h1q = (const float4*)h1p;

    for (int t = 0; t < TT; ++t) {
        // ---- phase A: z0 = Z0x[b,t] + h0@U0 ; zu = h1@U1 ----
        float a0a = zrow[(size_t)t * G4], a0b = 0.f;
        float aua = 0.f, aub = 0.f;
        #pragma unroll
        for (int q = 0; q < 16; q += 2) {
            float4 hva = h0q[q], hvb = h0q[q + 1];
            const f16x2* pa = (const f16x2*)&hva;
            const f16x2* pb = (const f16x2*)&hvb;
            a0a = __builtin_amdgcn_fdot2(pa[0], u0c[4 * q + 0], a0a, false);
            a0a = __builtin_amdgcn_fdot2(pa[1], u0c[4 * q + 1], a0a, false);
            a0a = __builtin_amdgcn_fdot2(pa[2], u0c[4 * q + 2], a0a, false);
            a0a = __builtin_amdgcn_fdot2(pa[3], u0c[4 * q + 3], a0a, false);
            a0b = __builtin_amdgcn_fdot2(pb[0], u0c[4 * q + 4], a0b, false);
            a0b = __builtin_amdgcn_fdot2(pb[1], u0c[4 * q + 5], a0b, false);
            a0b = __builtin_amdgcn_fdot2(pb[2], u0c[4 * q + 6], a0b, false);
            a0b = __builtin_amdgcn_fdot2(pb[3], u0c[4 * q + 7], a0b, false);
        }
        #pragma unroll
        for (int q = 0; q < 16; q += 2) {
            float4 hva = h1q[q], hvb = h1q[q + 1];
            const f16x2* pa = (const f16x2*)&hva;
            const f16x2* pb = (const f16x2*)&hvb;
            aua = __builtin_amdgcn_fdot2(pa[0], u1c[4 * q + 0], aua, false);
            aua = __builtin_amdgcn_fdot2(pa[1], u1c[4 * q + 1], aua, false);
            aua = __builtin_amdgcn_fdot2(pa[2], u1c[4 * q + 2], aua, false);
            aua = __builtin_amdgcn_fdot2(pa[3], u1c[4 * q + 3], aua, false);
            aub = __builtin_amdgcn_fdot2(pb[0], u1c[4 * q + 4], aub, false);
            aub = __builtin_amdgcn_fdot2(pb[1], u1c[4 * q + 5], aub, false);
            aub = __builtin_amdgcn_fdot2(pb[2], u1c[4 * q + 6], aub, false);
            aub = __builtin_amdgcn_fdot2(pb[3], u1c[4 * q + 7], aub, false);
        }
        zb[tid] = a0a + a0b;
        zu[tid] = aua + aub;
        __syncthreads();

        // ---- phase B: layer-0 gates -> h0_t ----
        if (tid < HD) {
            float zi = zb[tid], zf = zb[HD + tid], zc = zb[2 * HD + tid], zo = zb[3 * HD + tid];
            float ig = 1.f / (1.f + expf(-zi));
            float fg = 1.f / (1.f + expf(-zf));
            float og = 1.f / (1.f + expf(-zo));
            c0 = fg * c0 + ig * tanhf(zc);
            h0p[tid] = (_Float16)(og * tanhf(c0));
        }
        __syncthreads();

        // ---- phase C: z1 = b1 + zu + h0_t@W1 ----
        float a1a = b1c + zu[tid], a1b = 0.f;
        #pragma unroll
        for (int q = 0; q < 16; q += 2) {
            float4 hva = h0q[q], hvb = h0q[q + 1];
            const f16x2* pa = (const f16x2*)&hva;
            const f16x2* pb = (const f16x2*)&hvb;
            a1a = __builtin_amdgcn_fdot2(pa[0], w1c[4 * q + 0], a1a, false);
            a1a = __builtin_amdgcn_fdot2(pa[1], w1c[4 * q + 1], a1a, false);
            a1a = __builtin_amdgcn_fdot2(pa[2], w1c[4 * q + 2], a1a, false);
            a1a = __builtin_amdgcn_fdot2(pa[3], w1c[4 * q + 3], a1a, false);
            a1b = __builtin_amdgcn_fdot2(pb[0], w1c[4 * q + 4], a1b, false);
            a1b = __builtin_amdgcn_fdot2(pb[1], w1c[4 * q + 5], a1b, false);
            a1b = __builtin_amdgcn_fdot2(pb[2], w1c[4 * q + 6], a1b, false);
            a1b = __builtin_amdgcn_fdot2(pb[3], w1c[4 * q + 7], a1b, false);
        }
        zb[tid] = a1a + a1b;
        __syncthreads();

        // ---- phase D: layer-1 gates -> h1_t, y ----
        if (tid < HD) {
            float zi = zb[tid], zf = zb[HD + tid], zc = zb[2 * HD + tid], zo = zb[3 * HD + tid];
            float ig = 1.f / (1.f + expf(-zi));
            float fg = 1.f / (1.f + expf(-zf));
            float og = 1.f / (1.f + expf(-zo));
            c1 = fg * c1 + ig * tanhf(zc);
            float hn = og * tanhf(c1);
            h1p[tid] = (_Float16)hn;
            y[(size_t)(b * TT + t) * HD + tid] = hn;
        }
        __syncthreads();
    }
}

// ---------------- Prep: split Wd into f16 hi/lo, MFMA-fragment-packed ----------------
// layout: chunk = ntile*4 + kstep; dst[chunk*512 + lane*8 + j] (f16)
// src: Wd[k][n], k = kstep*32 + (lane>>4)*8 + j, n = ntile*16 + (lane&15)
__global__ __launch_bounds__(256) void k_wsplit(
    const float* __restrict__ Wd, _Float16* __restrict__ Whi, _Float16* __restrict__ Wlo)
{
    const int g = blockIdx.x * 256 + threadIdx.x;
    const int chunk = g >> 6;           // 0..7999
    const int lane = g & 63;
    const int ntile = chunk >> 2;
    const int kstep = chunk & 3;
    const int n = ntile * 16 + (lane & 15);
    const int kb = kstep * 32 + (lane >> 4) * 8;
    _Float16 hi[8], lo[8];
    #pragma unroll
    for (int j = 0; j < 8; ++j) {
        float v = Wd[(size_t)(kb + j) * NV + n];
        hi[j] = (_Float16)v;
        lo[j] = (_Float16)(v - (float)hi[j]);
    }
    *(float4*)&Whi[(size_t)chunk * 512 + lane * 8] = *(const float4*)hi;
    *(float4*)&Wlo[(size_t)chunk * 512 + lane * 8] = *(const float4*)lo;
}

// ---------------- Prep: split y into f16 hi/lo, MFMA-fragment-packed ----------------
// chunk = mtile*4 + kstep (mtile 0..255); src y[mtile*16 + (lane&15)][kstep*32 + (lane>>4)*8 + j]
__global__ __launch_bounds__(256) void k_ysplit(
    const float* __restrict__ y, _Float16* __restrict__ yhi, _Float16* __restrict__ ylo)
{
    const int g = blockIdx.x * 256 + threadIdx.x;
    const int chunk = g >> 6;           // 0..1023
    const int lane = g & 63;
    const int mtile = chunk >> 2;
    const int kstep = chunk & 3;
    const int row = mtile * 16 + (lane & 15);
    const int kb = kstep * 32 + (lane >> 4) * 8;
    _Float16 hi[8], lo[8];
    #pragma unroll
    for (int j = 0; j < 8; ++j) {
        float v = y[(size_t)row * HD + kb + j];
        hi[j] = (_Float16)v;
        lo[j] = (_Float16)(v - (float)hi[j]);
    }
    *(float4*)&yhi[(size_t)chunk * 512 + lane * 8] = *(const float4*)hi;
    *(float4*)&ylo[(size_t)chunk * 512 + lane * 8] = *(const float4*)lo;
}

// ---------------- Kernel C (MFMA): out = y @ Wd + bd via f16 hi/lo split ----------------
// block = 4 waves; wave w owns mtile = bx*4+w, 20 ntiles starting at by*20.
// C = Ah*Bh + Ah*Bl + Al*Bh  (lo*lo dropped, ~2^-24 rel)
__global__ __launch_bounds__(256) void k_dense_mfma(
    const _Float16* __restrict__ yhi, const _Float16* __restrict__ ylo,
    const _Float16* __restrict__ Whi, const _Float16* __restrict__ Wlo,
    const float* __restrict__ bd, float* __restrict__ out)
{
    const int tid = threadIdx.x;
    const int w = tid >> 6;
    const int lane = tid & 63;
    const int mtile = blockIdx.x * 4 + w;
    const int nt0 = blockIdx.y * 20;

    // A fragments: 4 ksteps x (hi,lo)
    f16x8 Ah[4], Al[4];
    #pragma unroll
    for (int k = 0; k < 4; ++k) {
        Ah[k] = *(const f16x8*)&yhi[(size_t)(mtile * 4 + k) * 512 + lane * 8];
        Al[k] = *(const f16x8*)&ylo[(size_t)(mtile * 4 + k) * 512 + lane * 8];
    }

    const int m0 = mtile * 16;
    const int r0 = (lane >> 4) * 4;          // C/D row group (m89 mapping)

    for (int nt = 0; nt < 20; ++nt) {
        const int ntile = nt0 + nt;
        const size_t cb = (size_t)ntile * 4 * 512 + lane * 8;
        f16x8 Bh[4], Bl[4];
        #pragma unroll
        for (int k = 0; k < 4; ++k) {
            Bh[k] = *(const f16x8*)&Whi[cb + k * 512];
            Bl[k] = *(const f16x8*)&Wlo[cb + k * 512];
        }
        f32x4 acc0 = {0.f, 0.f, 0.f, 0.f};
        f32x4 acc1 = {0.f, 0.f, 0.f, 0.f};
        #pragma unroll
        for (int k = 0; k < 4; ++k) {
            acc0 = __builtin_amdgcn_mfma_f32_16x16x32_f16(Ah[k], Bh[k], acc0, 0, 0, 0);
            acc1 = __builtin_amdgcn_mfma_f32_16x16x32_f16(Ah[k], Bl[k], acc1, 0, 0, 0);
            acc1 = __builtin_amdgcn_mfma_f32_16x16x32_f16(Al[k], Bh[k], acc1, 0, 0, 0);
        }
        const int col = ntile * 16 + (lane & 15);
        const float bias = bd[col];
        #pragma unroll
        for (int reg = 0; reg < 4; ++reg) {
            out[(size_t)(m0 + r0 + reg) * NV + col] = acc0[reg] + acc1[reg] + bias;
        }
    }
}

// ---------------- Kernel C (fallback, fp32 vector) ----------------
__global__ __launch_bounds__(256) void k_dense(
    const float* __restrict__ y, const float* __restrict__ Wd,
    const float* __restrict__ bd, float* __restrict__ out)
{
    __shared__ float ys[64 * HD];
    const int r0 = blockIdx.x * 64;
    const int v0 = blockIdx.y * 128;
    const int tid = threadIdx.x;
    for (int idx = tid; idx < 64 * HD; idx += 256) ys[idx] = y[(size_t)r0 * HD + idx];
    __syncthreads();
    const int tx = tid & 31;
    const int ty = tid >> 5;
    const int v = v0 + tx * 4;
    float4 bd4 = *(const float4*)&bd[v];
    float acc[8][4] = {};
    const float* yrow = &ys[(ty * 8) * HD];
    #pragma unroll 4
    for (int e = 0; e < HD; ++e) {
        float4 wv = *(const float4*)&Wd[(size_t)e * NV + v];
        #pragma unroll
        for (int j = 0; j < 8; ++j) {
            float yv = yrow[j * HD + e];
            acc[j][0] = fmaf(yv, wv.x, acc[j][0]);
            acc[j][1] = fmaf(yv, wv.y, acc[j][1]);
            acc[j][2] = fmaf(yv, wv.z, acc[j][2]);
            acc[j][3] = fmaf(yv, wv.w, acc[j][3]);
        }
    }
    #pragma unroll
    for (int j = 0; j < 8; ++j) {
        int rr = r0 + ty * 8 + j;
        float4 o4;
        o4.x = acc[j][0] + bd4.x;
        o4.y = acc[j][1] + bd4.y;
        o4.z = acc[j][2] + bd4.z;
        o4.w = acc[j][3] + bd4.w;
        *(float4*)&out[(size_t)rr * NV + v] = o4;
    }
}

extern "C" void kernel_launch(void* const* d_in, const int* in_sizes, int n_in,
                              void* d_out, int out_size, void* d_ws, size_t ws_size,
                              hipStream_t stream)
{
    const int*   inputs = (const int*)  d_in[0];
    const float* emb    = (const float*)d_in[1];
    const float* W0     = (const float*)d_in[2];
    const float* U0     = (const float*)d_in[3];
    const float* b0     = (const float*)d_in[4];
    const float* W1     = (const float*)d_in[5];
    const float* U1     = (const float*)d_in[6];
    const float* b1     = (const float*)d_in[7];
    const float* Wd     = (const float*)d_in[8];
    const float* bd     = (const float*)d_in[9];
    float* out = (float*)d_out;

    // ws layout (MFMA path): Z0x 8MB | yy 2MB | Whi 8MB | Wlo 8MB | yhi 1MB | ylo 1MB
    const size_t Z0X_B = (size_t)8 * 1024 * 1024;
    const size_t YY_B  = (size_t)2 * 1024 * 1024;
    const size_t WSP_B = (size_t)8000 * 512 * 2;        // 8,192,000
    const size_t YSP_B = (size_t)1024 * 512 * 2;        // 1,048,576
    const size_t NEED  = Z0X_B + YY_B + 2 * WSP_B + 2 * YSP_B + 4096;

    char* ws = (char*)d_ws;

    if (ws_size >= NEED) {
        float*     Z0x = (float*)ws;
        float*     yy  = (float*)(ws + Z0X_B);
        _Float16*  Whi = (_Float16*)(ws + Z0X_B + YY_B);
        _Float16*  Wlo = (_Float16*)(ws + Z0X_B + YY_B + WSP_B);
        _Float16*  yhi = (_Float16*)(ws + Z0X_B + YY_B + 2 * WSP_B);
        _Float16*  ylo = (_Float16*)(ws + Z0X_B + YY_B + 2 * WSP_B + YSP_B);

        k_embed_w0<<<512, 256, 0, stream>>>(inputs, emb, W0, b0, Z0x);
        k_wsplit<<<2000, 256, 0, stream>>>(Wd, Whi, Wlo);
        k_lstm_f2<<<BB, 512, 0, stream>>>(Z0x, U0, W1, U1, b1, yy);
        k_ysplit<<<256, 256, 0, stream>>>(yy, yhi, ylo);
        k_dense_mfma<<<dim3(64, 100), 256, 0, stream>>>(yhi, ylo, Whi, Wlo, bd, out);
    } else {
        // small-ws fallback: Z0x in d_out tail, yy in ws, fp32 dense
        float* yy = (float*)ws;
        size_t out_bytes = (size_t)out_size * sizeof(float);
        float* Z0x = (float*)((char*)d_out + out_bytes - Z0X_B);

        k_embed_w0<<<512, 256, 0, stream>>>(inputs, emb, W0, b0, Z0x);
        k_lstm_f2<<<BB, 512, 0, stream>>>(Z0x, U0, W1, U1, b1, yy);
        k_dense<<<dim3(64, 250), 256, 0, stream>>>(yy, Wd, bd, out);
    }
}

// Round 7
// 659.217 us; speedup vs baseline: 1.3506x; 1.3506x over previous
//
#include <hip/hip_runtime.h>
#include <math.h>

#define BB 32
#define TT 128
#define EE 128
#define HD 128
#define G4 512   // 4*H
#define NV 32000

typedef _Float16 f16x2 __attribute__((ext_vector_type(2)));
typedef _Float16 f16x8 __attribute__((ext_vector_type(8)));
typedef float    f32x4 __attribute__((ext_vector_type(4)));

// ---------------- Kernel A (fused): blocks 0..1999 split Wd, 2000..2511 embed ----------------
// wsplit: chunk = ntile*4 + kstep; dst[chunk*512 + lane*8 + j] (f16)
//         src: Wd[k][n], k = kstep*32 + (lane>>4)*8 + j, n = ntile*16 + (lane&15)
__global__ __launch_bounds__(256) void k_prep(
    const int* __restrict__ inputs, const float* __restrict__ emb,
    const float* __restrict__ W0, const float* __restrict__ b0,
    float* __restrict__ Z0x,
    const float* __restrict__ Wd, _Float16* __restrict__ Whi, _Float16* __restrict__ Wlo)
{
    if (blockIdx.x < 2000) {
        // ---- Wd hi/lo split, MFMA-fragment-packed ----
        const int g = blockIdx.x * 256 + threadIdx.x;
        const int chunk = g >> 6;           // 0..7999
        const int lane = g & 63;
        const int ntile = chunk >> 2;
        const int kstep = chunk & 3;
        const int n = ntile * 16 + (lane & 15);
        const int kb = kstep * 32 + (lane >> 4) * 8;
        _Float16 hi[8], lo[8];
        #pragma unroll
        for (int j = 0; j < 8; ++j) {
            float v = Wd[(size_t)(kb + j) * NV + n];
            hi[j] = (_Float16)v;
            lo[j] = (_Float16)(v - (float)hi[j]);
        }
        *(float4*)&Whi[(size_t)chunk * 512 + lane * 8] = *(const float4*)hi;
        *(float4*)&Wlo[(size_t)chunk * 512 + lane * 8] = *(const float4*)lo;
        return;
    }
    // ---- embed + W0: Z0x = emb[inputs] @ W0 + b0 ----
    __shared__ float xs[8][EE];
    const int r0 = (blockIdx.x - 2000) * 8;
    const int tid = threadIdx.x;
    for (int i = tid; i < 8 * EE; i += 256) {
        int r = i >> 7, e = i & 127;
        int tok = inputs[r0 + r];
        xs[r][e] = emb[tok * EE + e];
    }
    __syncthreads();
    const int c2 = tid * 2;
    float2 bb2 = *(const float2*)&b0[c2];
    float acc[8][2];
    #pragma unroll
    for (int r = 0; r < 8; ++r) { acc[r][0] = bb2.x; acc[r][1] = bb2.y; }
    for (int e = 0; e < EE; ++e) {
        float2 w = *(const float2*)&W0[e * G4 + c2];
        #pragma unroll
        for (int r = 0; r < 8; ++r) {
            float x = xs[r][e];
            acc[r][0] = fmaf(x, w.x, acc[r][0]);
            acc[r][1] = fmaf(x, w.y, acc[r][1]);
        }
    }
    #pragma unroll
    for (int r = 0; r < 8; ++r) {
        float2 o2; o2.x = acc[r][0]; o2.y = acc[r][1];
        *(float2*)&Z0x[(size_t)(r0 + r) * G4 + c2] = o2;
    }
}

// ---------------- Kernel B: 2-layer LSTM, one block per batch ----------------
// ROUND-5 BODY VERBATIM (known no-spill at ~232 VGPR / 2 waves-per-SIMD).
// 32 blocks x 512 threads; f16 register-resident weight columns (192 VGPR);
// f32 accumulate via v_dot2_f32_f16; h through LDS as f16.
__global__ __launch_bounds__(512, 2) void k_lstm_f(
    const float* __restrict__ Z0x,
    const float* __restrict__ U0, const float* __restrict__ W1,
    const float* __restrict__ U1, const float* __restrict__ b1,
    float* __restrict__ y)
{
    const int b = blockIdx.x;
    const int tid = threadIdx.x;

    __shared__ _Float16 h0p[HD];   // packed h0_{t-1} (f16)
    __shared__ _Float16 h1p[HD];   // packed h1_{t-1} (f16)
    __shared__ float zb[G4];
    __shared__ float zu[G4];

    // register-resident f16 weight columns (192 VGPR)
    f16x2 u0c[64], w1c[64], u1c[64];
    #pragma unroll
    for (int e2 = 0; e2 < 64; ++e2) {
        u0c[e2] = f16x2{(_Float16)U0[(2 * e2) * G4 + tid], (_Float16)U0[(2 * e2 + 1) * G4 + tid]};
        w1c[e2] = f16x2{(_Float16)W1[(2 * e2) * G4 + tid], (_Float16)W1[(2 * e2 + 1) * G4 + tid]};
        u1c[e2] = f16x2{(_Float16)U1[(2 * e2) * G4 + tid], (_Float16)U1[(2 * e2 + 1) * G4 + tid]};
    }

    const float b1c = b1[tid];
    const float* __restrict__ zrow = Z0x + (size_t)b * TT * G4 + tid;

    float c0 = 0.f, c1 = 0.f;   // cell states (threads 0..127)
    if (tid < HD) { h0p[tid] = (_Float16)0.f; h1p[tid] = (_Float16)0.f; }
    __syncthreads();

    const f16x2* h0v = (const f16x2*)h0p;
    const f16x2* h1v = (const f16x2*)h1p;

    for (int t = 0; t < TT; ++t) {
        // ---- phase A: z0 = Z0x[b,t] + h0@U0 ; zu = h1@U1 ----
        float a0a = zrow[(size_t)t * G4], a0b = 0.f;
        float aua = 0.f, aub = 0.f;
        #pragma unroll
        for (int e2 = 0; e2 < 64; e2 += 2) {
            a0a = __builtin_amdgcn_fdot2(h0v[e2],     u0c[e2],     a0a, false);
            a0b = __builtin_amdgcn_fdot2(h0v[e2 + 1], u0c[e2 + 1], a0b, false);
            aua = __builtin_amdgcn_fdot2(h1v[e2],     u1c[e2],     aua, false);
            aub = __builtin_amdgcn_fdot2(h1v[e2 + 1], u1c[e2 + 1], aub, false);
        }
        zb[tid] = a0a + a0b;
        zu[tid] = aua + aub;
        __syncthreads();

        // ---- phase B: layer-0 gates -> h0_t (f16 to LDS) ----
        if (tid < HD) {
            float zi = zb[tid], zf = zb[HD + tid], zc = zb[2 * HD + tid], zo = zb[3 * HD + tid];
            float ig = 1.f / (1.f + expf(-zi));
            float fg = 1.f / (1.f + expf(-zf));
            float og = 1.f / (1.f + expf(-zo));
            c0 = fg * c0 + ig * tanhf(zc);
            h0p[tid] = (_Float16)(og * tanhf(c0));
        }
        __syncthreads();

        // ---- phase C: z1 = b1 + zu + h0_t@W1 ----
        float a1a = b1c + zu[tid], a1b = 0.f;
        #pragma unroll
        for (int e2 = 0; e2 < 64; e2 += 2) {
            a1a = __builtin_amdgcn_fdot2(h0v[e2],     w1c[e2],     a1a, false);
            a1b = __builtin_amdgcn_fdot2(h0v[e2 + 1], w1c[e2 + 1], a1b, false);
        }
        zb[tid] = a1a + a1b;
        __syncthreads();

        // ---- phase D: layer-1 gates -> h1_t (f16 to LDS), y (f32) ----
        if (tid < HD) {
            float zi = zb[tid], zf = zb[HD + tid], zc = zb[2 * HD + tid], zo = zb[3 * HD + tid];
            float ig = 1.f / (1.f + expf(-zi));
            float fg = 1.f / (1.f + expf(-zf));
            float og = 1.f / (1.f + expf(-zo));
            c1 = fg * c1 + ig * tanhf(zc);
            float hn = og * tanhf(c1);
            h1p[tid] = (_Float16)hn;
            y[(size_t)(b * TT + t) * HD + tid] = hn;
        }
        __syncthreads();
    }
}

// ---------------- Prep: split y into f16 hi/lo, MFMA-fragment-packed ----------------
__global__ __launch_bounds__(256) void k_ysplit(
    const float* __restrict__ y, _Float16* __restrict__ yhi, _Float16* __restrict__ ylo)
{
    const int g = blockIdx.x * 256 + threadIdx.x;
    const int chunk = g >> 6;           // 0..1023
    const int lane = g & 63;
    const int mtile = chunk >> 2;
    const int kstep = chunk & 3;
    const int row = mtile * 16 + (lane & 15);
    const int kb = kstep * 32 + (lane >> 4) * 8;
    _Float16 hi[8], lo[8];
    #pragma unroll
    for (int j = 0; j < 8; ++j) {
        float v = y[(size_t)row * HD + kb + j];
        hi[j] = (_Float16)v;
        lo[j] = (_Float16)(v - (float)hi[j]);
    }
    *(float4*)&yhi[(size_t)chunk * 512 + lane * 8] = *(const float4*)hi;
    *(float4*)&ylo[(size_t)chunk * 512 + lane * 8] = *(const float4*)lo;
}

// ---------------- Kernel C (MFMA): out = y @ Wd + bd via f16 hi/lo split ----------------
__global__ __launch_bounds__(256) void k_dense_mfma(
    const _Float16* __restrict__ yhi, const _Float16* __restrict__ ylo,
    const _Float16* __restrict__ Whi, const _Float16* __restrict__ Wlo,
    const float* __restrict__ bd, float* __restrict__ out)
{
    const int tid = threadIdx.x;
    const int w = tid >> 6;
    const int lane = tid & 63;
    const int mtile = blockIdx.x * 4 + w;
    const int nt0 = blockIdx.y * 20;

    f16x8 Ah[4], Al[4];
    #pragma unroll
    for (int k = 0; k < 4; ++k) {
        Ah[k] = *(const f16x8*)&yhi[(size_t)(mtile * 4 + k) * 512 + lane * 8];
        Al[k] = *(const f16x8*)&ylo[(size_t)(mtile * 4 + k) * 512 + lane * 8];
    }

    const int m0 = mtile * 16;
    const int r0 = (lane >> 4) * 4;          // C/D row group (m89 mapping)

    for (int nt = 0; nt < 20; ++nt) {
        const int ntile = nt0 + nt;
        const size_t cb = (size_t)ntile * 4 * 512 + lane * 8;
        f16x8 Bh[4], Bl[4];
        #pragma unroll
        for (int k = 0; k < 4; ++k) {
            Bh[k] = *(const f16x8*)&Whi[cb + k * 512];
            Bl[k] = *(const f16x8*)&Wlo[cb + k * 512];
        }
        f32x4 acc0 = {0.f, 0.f, 0.f, 0.f};
        f32x4 acc1 = {0.f, 0.f, 0.f, 0.f};
        #pragma unroll
        for (int k = 0; k < 4; ++k) {
            acc0 = __builtin_amdgcn_mfma_f32_16x16x32_f16(Ah[k], Bh[k], acc0, 0, 0, 0);
            acc1 = __builtin_amdgcn_mfma_f32_16x16x32_f16(Ah[k], Bl[k], acc1, 0, 0, 0);
            acc1 = __builtin_amdgcn_mfma_f32_16x16x32_f16(Al[k], Bh[k], acc1, 0, 0, 0);
        }
        const int col = ntile * 16 + (lane & 15);
        const float bias = bd[col];
        #pragma unroll
        for (int reg = 0; reg < 4; ++reg) {
            out[(size_t)(m0 + r0 + reg) * NV + col] = acc0[reg] + acc1[reg] + bias;
        }
    }
}

// ---------------- Kernel C (fallback, fp32 vector) ----------------
__global__ __launch_bounds__(256) void k_dense(
    const float* __restrict__ y, const float* __restrict__ Wd,
    const float* __restrict__ bd, float* __restrict__ out)
{
    __shared__ float ys[64 * HD];
    const int r0 = blockIdx.x * 64;
    const int v0 = blockIdx.y * 128;
    const int tid = threadIdx.x;
    for (int idx = tid; idx < 64 * HD; idx += 256) ys[idx] = y[(size_t)r0 * HD + idx];
    __syncthreads();
    const int tx = tid & 31;
    const int ty = tid >> 5;
    const int v = v0 + tx * 4;
    float4 bd4 = *(const float4*)&bd[v];
    float acc[8][4] = {};
    const float* yrow = &ys[(ty * 8) * HD];
    #pragma unroll 4
    for (int e = 0; e < HD; ++e) {
        float4 wv = *(const float4*)&Wd[(size_t)e * NV + v];
        #pragma unroll
        for (int j = 0; j < 8; ++j) {
            float yv = yrow[j * HD + e];
            acc[j][0] = fmaf(yv, wv.x, acc[j][0]);
            acc[j][1] = fmaf(yv, wv.y, acc[j][1]);
            acc[j][2] = fmaf(yv, wv.z, acc[j][2]);
            acc[j][3] = fmaf(yv, wv.w, acc[j][3]);
        }
    }
    #pragma unroll
    for (int j = 0; j < 8; ++j) {
        int rr = r0 + ty * 8 + j;
        float4 o4;
        o4.x = acc[j][0] + bd4.x;
        o4.y = acc[j][1] + bd4.y;
        o4.z = acc[j][2] + bd4.z;
        o4.w = acc[j][3] + bd4.w;
        *(float4*)&out[(size_t)rr * NV + v] = o4;
    }
}

extern "C" void kernel_launch(void* const* d_in, const int* in_sizes, int n_in,
                              void* d_out, int out_size, void* d_ws, size_t ws_size,
                              hipStream_t stream)
{
    const int*   inputs = (const int*)  d_in[0];
    const float* emb    = (const float*)d_in[1];
    const float* W0     = (const float*)d_in[2];
    const float* U0     = (const float*)d_in[3];
    const float* b0     = (const float*)d_in[4];
    const float* W1     = (const float*)d_in[5];
    const float* U1     = (const float*)d_in[6];
    const float* b1     = (const float*)d_in[7];
    const float* Wd     = (const float*)d_in[8];
    const float* bd     = (const float*)d_in[9];
    float* out = (float*)d_out;

    // ws layout (MFMA path): Z0x 8MB | yy 2MB | Whi 8MB | Wlo 8MB | yhi 1MB | ylo 1MB
    const size_t Z0X_B = (size_t)8 * 1024 * 1024;
    const size_t YY_B  = (size_t)2 * 1024 * 1024;
    const size_t WSP_B = (size_t)8000 * 512 * 2;        // 8,192,000
    const size_t YSP_B = (size_t)1024 * 512 * 2;        // 1,048,576
    const size_t NEED  = Z0X_B + YY_B + 2 * WSP_B + 2 * YSP_B + 4096;

    char* ws = (char*)d_ws;

    if (ws_size >= NEED) {
        float*     Z0x = (float*)ws;
        float*     yy  = (float*)(ws + Z0X_B);
        _Float16*  Whi = (_Float16*)(ws + Z0X_B + YY_B);
        _Float16*  Wlo = (_Float16*)(ws + Z0X_B + YY_B + WSP_B);
        _Float16*  yhi = (_Float16*)(ws + Z0X_B + YY_B + 2 * WSP_B);
        _Float16*  ylo = (_Float16*)(ws + Z0X_B + YY_B + 2 * WSP_B + YSP_B);

        k_prep<<<2512, 256, 0, stream>>>(inputs, emb, W0, b0, Z0x, Wd, Whi, Wlo);
        k_lstm_f<<<BB, 512, 0, stream>>>(Z0x, U0, W1, U1, b1, yy);
        k_ysplit<<<256, 256, 0, stream>>>(yy, yhi, ylo);
        k_dense_mfma<<<dim3(64, 100), 256, 0, stream>>>(yhi, ylo, Whi, Wlo, bd, out);
    } else {
        // small-ws fallback: Z0x in d_out tail, yy in ws, fp32 dense
        float* yy = (float*)ws;
        size_t out_bytes = (size_t)out_size * sizeof(float);
        float* Z0x = (float*)((char*)d_out + out_bytes - Z0X_B);

        k_prep<<<2512, 256, 0, stream>>>(inputs, emb, W0, b0, Z0x,
                                         Wd, (_Float16*)ws, (_Float16*)ws);  // wsplit result unused
        k_lstm_f<<<BB, 512, 0, stream>>>(Z0x, U0, W1, U1, b1, yy);
        k_dense<<<dim3(64, 250), 256, 0, stream>>>(yy, Wd, bd, out);
    }
}